// Round 1
// baseline (1265.750 us; speedup 1.0000x reference)
//
#include <hip/hip_runtime.h>
#include <stdint.h>

#define D_MODEL 1024
#define D_FF    4096
#define NHEADS  16
#define HD      64
#define LN_EPS  1e-5f

using u16 = unsigned short;
typedef __bf16 bf16x8 __attribute__((ext_vector_type(8)));
typedef float  f32x4  __attribute__((ext_vector_type(4)));

typedef __attribute__((address_space(1))) uint32_t as1_u32;
typedef __attribute__((address_space(3))) uint32_t as3_u32;

__device__ __forceinline__ u16 f2bf(float f) {
  union { float f; uint32_t u; } v; v.f = f;
  uint32_t r = v.u + 0x7FFFu + ((v.u >> 16) & 1u);
  return (u16)(r >> 16);
}

// async global->LDS, 16B per lane; LDS dest must be wave-uniform base (+lane*16 implicit)
__device__ __forceinline__ void gl_lds16(const void* g, void* l) {
  __builtin_amdgcn_global_load_lds((const as1_u32*)(uintptr_t)g,
                                   (as3_u32*)(uint32_t)(uintptr_t)l, 16, 0, 0);
}

// ---------------- transpose + cast: W (K x N, f32) -> Wt (N x K, bf16) ----------------
__global__ __launch_bounds__(256)
void transpose_cast(const float* __restrict__ W, u16* __restrict__ Wt, int K, int N) {
  __shared__ float t[32][33];
  const int k0 = blockIdx.x * 32, n0 = blockIdx.y * 32;
  const int x = threadIdx.x & 31, y = threadIdx.x >> 5; // y in 0..7
#pragma unroll
  for (int j = 0; j < 32; j += 8)
    t[y + j][x] = W[(size_t)(k0 + y + j) * N + (n0 + x)];
  __syncthreads();
#pragma unroll
  for (int j = 0; j < 32; j += 8)
    Wt[(size_t)(n0 + y + j) * K + (k0 + x)] = f2bf(t[x][y + j]);
}

// ---------------- elementwise cast f32 -> bf16 ----------------
__global__ __launch_bounds__(256)
void cast_f32_bf16(const float* __restrict__ in, u16* __restrict__ out, int n4) {
  int i = blockIdx.x * 256 + threadIdx.x;
  if (i < n4) {
    float4 v = ((const float4*)in)[i];
    ushort4 o;
    o.x = f2bf(v.x); o.y = f2bf(v.y); o.z = f2bf(v.z); o.w = f2bf(v.w);
    ((ushort4*)out)[i] = o;
  }
}

// ---------------- LayerNorm (fp32 in, bf16 out), one block per row, D=1024 ----------------
__global__ __launch_bounds__(256)
void ln_bf16(const float* __restrict__ x, const float* __restrict__ g,
             const float* __restrict__ bta, u16* __restrict__ out) {
  const int row = blockIdx.x;
  const int tid = threadIdx.x;
  const float4 v = ((const float4*)(x + (size_t)row * D_MODEL))[tid];
  float s  = v.x + v.y + v.z + v.w;
  float s2 = v.x * v.x + v.y * v.y + v.z * v.z + v.w * v.w;
#pragma unroll
  for (int off = 1; off < 64; off <<= 1) {
    s  += __shfl_xor(s, off);
    s2 += __shfl_xor(s2, off);
  }
  __shared__ float sm[8];
  const int wave = tid >> 6, lane = tid & 63;
  if (lane == 0) { sm[wave] = s; sm[4 + wave] = s2; }
  __syncthreads();
  s  = sm[0] + sm[1] + sm[2] + sm[3];
  s2 = sm[4] + sm[5] + sm[6] + sm[7];
  const float mean = s * (1.f / D_MODEL);
  const float var  = s2 * (1.f / D_MODEL) - mean * mean;
  const float rstd = rsqrtf(var + LN_EPS);
  const float4 gv = ((const float4*)g)[tid];
  const float4 bv = ((const float4*)bta)[tid];
  ushort4 o;
  o.x = f2bf((v.x - mean) * rstd * gv.x + bv.x);
  o.y = f2bf((v.y - mean) * rstd * gv.y + bv.y);
  o.z = f2bf((v.z - mean) * rstd * gv.z + bv.z);
  o.w = f2bf((v.w - mean) * rstd * gv.w + bv.w);
  ((ushort4*)(out + (size_t)row * D_MODEL))[tid] = o;
}

// ---------------- GEMM: C[M,N] = A[M,K](bf16) * Wt[N,K]^T(bf16) + bias, epilogues ----------------
// EPI 0: out bf16;  EPI 1: relu -> bf16;  EPI 2: f32 out = acc + bias + resid
template<int EPI>
__global__ __launch_bounds__(256, 2)
void gemm_bf16(const u16* __restrict__ A, const u16* __restrict__ Wt,
               const float* __restrict__ bias, const float* resid,
               u16* __restrict__ outb, float* outf,
               int M, int N, int K) {
  __shared__ u16 lA[128 * 32];
  __shared__ u16 lB[128 * 32];
  const int tid  = threadIdx.x;
  const int lane = tid & 63;
  const int wave = tid >> 6;
  const int wr = wave >> 1, wc = wave & 1;
  const int lr = lane & 15, lg = lane >> 4;
  const int row0 = blockIdx.x * 128, col0 = blockIdx.y * 128;

  // staging: LDS [128][32] bf16 linear; thread covers 16B at linear byte tid*16 (+4096 for chunk 1)
  const char* pa = (const char*)A  + ((size_t)(row0 + (tid >> 2)) * K + (size_t)(tid & 3) * 8) * 2;
  const char* pb = (const char*)Wt + ((size_t)(col0 + (tid >> 2)) * K + (size_t)(tid & 3) * 8) * 2;
  const size_t rowskip = (size_t)64 * K * 2;
  char* la = (char*)lA + wave * 1024;
  char* lb = (char*)lB + wave * 1024;

  f32x4 acc[4][4] = {};
  const int ksteps = K >> 5;
  for (int kt = 0; kt < ksteps; ++kt) {
    gl_lds16(pa, la);
    gl_lds16(pa + rowskip, la + 4096);
    gl_lds16(pb, lb);
    gl_lds16(pb + rowskip, lb + 4096);
    pa += 64; pb += 64;
    __syncthreads();
    bf16x8 af[4], bfr[4];
#pragma unroll
    for (int m = 0; m < 4; ++m)
      af[m] = *(const bf16x8*)((const char*)lA + (wr * 64 + m * 16 + lr) * 64 + lg * 16);
#pragma unroll
    for (int n = 0; n < 4; ++n)
      bfr[n] = *(const bf16x8*)((const char*)lB + (wc * 64 + n * 16 + lr) * 64 + lg * 16);
#pragma unroll
    for (int m = 0; m < 4; ++m)
#pragma unroll
      for (int n = 0; n < 4; ++n)
        acc[m][n] = __builtin_amdgcn_mfma_f32_16x16x32_bf16(af[m], bfr[n], acc[m][n], 0, 0, 0);
    __syncthreads();
  }

#pragma unroll
  for (int m = 0; m < 4; ++m) {
    const int grow = row0 + wr * 64 + m * 16 + lg * 4;
#pragma unroll
    for (int n = 0; n < 4; ++n) {
      const int gcol = col0 + wc * 64 + n * 16 + lr;
      const float bv = bias[gcol];
#pragma unroll
      for (int r = 0; r < 4; ++r) {
        const size_t idx = (size_t)(grow + r) * N + gcol;
        float v = acc[m][n][r] + bv;
        if (EPI == 0)      outb[idx] = f2bf(v);
        else if (EPI == 1) outb[idx] = f2bf(v > 0.f ? v : 0.f);
        else               outf[idx] = v + resid[idx];
      }
    }
  }
}

// ---------------- Flash attention: 64 q-rows per block, 64-wide KV tiles ----------------
// Q,K,V,O: (B*rows, D_MODEL) bf16, head h at column h*HD
template<bool CAUSAL>
__global__ __launch_bounds__(256, 2)
void attn_kernel(const u16* __restrict__ Q, const u16* __restrict__ Kb,
                 const u16* __restrict__ Vb, u16* __restrict__ O,
                 int T, int S) {
  __shared__ u16 lQ[64 * 64];
  __shared__ u16 lK[64 * 64];
  __shared__ u16 lVt[64 * 64];   // transposed: [d][key]
  __shared__ u16 lP[4 * 16 * 64]; // per-wave 16x64

  const int bh = blockIdx.y;
  const int b = bh / NHEADS, h = bh % NHEADS;
  const int q0 = blockIdx.x * 64;
  const int tid = threadIdx.x, lane = tid & 63, wave = tid >> 6;
  const int lr = lane & 15, lg = lane >> 4;

  const u16* Qbase = Q  + (size_t)(b * T) * D_MODEL + h * HD;
  const u16* Kbase = Kb + (size_t)(b * S) * D_MODEL + h * HD;
  const u16* Vbase = Vb + (size_t)(b * S) * D_MODEL + h * HD;
  const size_t rskip = (size_t)32 * D_MODEL * 2; // 32 rows in bytes

  // stage Q tile (64 rows x 64 cols bf16, 128B/row)
  {
    const char* src = (const char*)(Qbase + (size_t)(q0 + (tid >> 3)) * D_MODEL) + (tid & 7) * 16;
    char* dst = (char*)lQ + wave * 1024;
    gl_lds16(src, dst);
    gl_lds16(src + rskip, dst + 4096);
  }

  f32x4 oacc[4] = {};
  float m_run[4], l_run[4];
#pragma unroll
  for (int r = 0; r < 4; ++r) { m_run[r] = -1e30f; l_run[r] = 0.f; }

  const int ktEnd = CAUSAL ? (q0 / 64 + 1) : (S / 64);
  for (int kt = 0; kt < ktEnd; ++kt) {
    // stage K tile
    {
      const char* src = (const char*)(Kbase + (size_t)(kt * 64 + (tid >> 3)) * D_MODEL) + (tid & 7) * 16;
      char* dst = (char*)lK + wave * 1024;
      gl_lds16(src, dst);
      gl_lds16(src + rskip, dst + 4096);
    }
    // stage V transposed (manual)
    {
      const u16* src = Vbase + (size_t)(kt * 64 + (tid >> 3)) * D_MODEL + (tid & 7) * 8;
      union { uint4 q; u16 s[8]; } v0, v1;
      v0.q = *(const uint4*)src;
      v1.q = *(const uint4*)(src + 32 * D_MODEL);
      const int key = tid >> 3, dbase = (tid & 7) * 8;
#pragma unroll
      for (int j = 0; j < 8; ++j) {
        lVt[(dbase + j) * 64 + key]      = v0.s[j];
        lVt[(dbase + j) * 64 + key + 32] = v1.s[j];
      }
    }
    __syncthreads();

    // QK^T for this wave's 16 rows x 64 cols
    f32x4 s[4];
    {
      bf16x8 qf[2];
#pragma unroll
      for (int kk = 0; kk < 2; ++kk)
        qf[kk] = *(const bf16x8*)((const char*)lQ + (wave * 16 + lr) * 128 + kk * 64 + lg * 16);
#pragma unroll
      for (int n = 0; n < 4; ++n) {
        f32x4 z = {};
#pragma unroll
        for (int kk = 0; kk < 2; ++kk) {
          bf16x8 kf = *(const bf16x8*)((const char*)lK + (n * 16 + lr) * 128 + kk * 64 + lg * 16);
          z = __builtin_amdgcn_mfma_f32_16x16x32_bf16(qf[kk], kf, z, 0, 0, 0);
        }
        s[n] = z;
      }
    }
    const float scale = 0.125f; // 1/sqrt(64)
    const bool needMask = CAUSAL && (kt * 64 + 63 > q0);
#pragma unroll
    for (int n = 0; n < 4; ++n)
#pragma unroll
      for (int r = 0; r < 4; ++r) {
        float v = s[n][r] * scale;
        if (needMask) {
          int qpos = q0 + wave * 16 + lg * 4 + r;
          int kpos = kt * 64 + n * 16 + lr;
          if (kpos > qpos) v = -1e30f;
        }
        s[n][r] = v;
      }
    // online softmax (per row; row owned by the 16 lanes with equal lg, at reg r)
#pragma unroll
    for (int r = 0; r < 4; ++r) {
      float mx = fmaxf(fmaxf(s[0][r], s[1][r]), fmaxf(s[2][r], s[3][r]));
      mx = fmaxf(mx, __shfl_xor(mx, 1));
      mx = fmaxf(mx, __shfl_xor(mx, 2));
      mx = fmaxf(mx, __shfl_xor(mx, 4));
      mx = fmaxf(mx, __shfl_xor(mx, 8));
      const float mn = fmaxf(m_run[r], mx);
      const float scl = __expf(m_run[r] - mn);
      m_run[r] = mn;
      float sum = 0.f;
#pragma unroll
      for (int n = 0; n < 4; ++n) {
        float pv = __expf(s[n][r] - mn);
        s[n][r] = pv;
        sum += pv;
      }
      sum += __shfl_xor(sum, 1);
      sum += __shfl_xor(sum, 2);
      sum += __shfl_xor(sum, 4);
      sum += __shfl_xor(sum, 8);
      l_run[r] = l_run[r] * scl + sum;
#pragma unroll
      for (int n2 = 0; n2 < 4; ++n2) oacc[n2][r] *= scl;
    }
    // write P (bf16) to this wave's LDS region
#pragma unroll
    for (int r = 0; r < 4; ++r)
#pragma unroll
      for (int n = 0; n < 4; ++n)
        lP[wave * 1024 + (lg * 4 + r) * 64 + n * 16 + lr] = f2bf(s[n][r]);
    asm volatile("s_waitcnt lgkmcnt(0)" ::: "memory");
    // PV: oacc += P(16x64) * V(64x64)
#pragma unroll
    for (int kk = 0; kk < 2; ++kk) {
      bf16x8 pf = *(const bf16x8*)((const char*)lP + wave * 2048 + lr * 128 + kk * 64 + lg * 16);
#pragma unroll
      for (int n = 0; n < 4; ++n) {
        bf16x8 vf = *(const bf16x8*)((const char*)lVt + (n * 16 + lr) * 128 + kk * 64 + lg * 16);
        oacc[n] = __builtin_amdgcn_mfma_f32_16x16x32_bf16(pf, vf, oacc[n], 0, 0, 0);
      }
    }
    __syncthreads();
  }

  u16* Obase = O + (size_t)(b * T + q0) * D_MODEL + h * HD;
#pragma unroll
  for (int n = 0; n < 4; ++n)
#pragma unroll
    for (int r = 0; r < 4; ++r) {
      float v = oacc[n][r] / l_run[r];
      Obase[(size_t)(wave * 16 + lg * 4 + r) * D_MODEL + n * 16 + lr] = f2bf(v);
    }
}

// ---------------- host ----------------
extern "C" void kernel_launch(void* const* d_in, const int* in_sizes, int n_in,
                              void* d_out, int out_size, void* d_ws, size_t ws_size,
                              hipStream_t stream) {
  (void)in_sizes; (void)n_in; (void)out_size; (void)ws_size;
  const int B = 4, T = 2048, S = 2048, Dm = 1024, F = 4096;
  const int M = B * T;

  const float* x   = (const float*)d_in[0];
  const float* enc = (const float*)d_in[1];
  const float* W_in[10] = {
    (const float*)d_in[2],  (const float*)d_in[4],  (const float*)d_in[6],  (const float*)d_in[8],
    (const float*)d_in[10], (const float*)d_in[12], (const float*)d_in[14], (const float*)d_in[16],
    (const float*)d_in[18], (const float*)d_in[20]
  };

  char* p = (char*)d_ws;
  auto take = [&](size_t bytes) { char* r = p; p += (bytes + 255) & ~(size_t)255; return r; };
  u16* wt[10];
  for (int i = 0; i < 8; ++i) wt[i] = (u16*)take((size_t)Dm * Dm * 2);
  wt[8] = (u16*)take((size_t)F * Dm * 2);   // ff1T: F x Dm
  wt[9] = (u16*)take((size_t)Dm * F * 2);   // ff2T: Dm x F
  u16*   h    = (u16*)take((size_t)M * Dm * 2);
  u16*   encb = (u16*)take((size_t)M * Dm * 2);
  float* xc   = (float*)take((size_t)M * Dm * 4);
  u16*   region = (u16*)take((size_t)M * F * 2);   // q/k/v/attn OR ffmid
  u16* qb = region;
  u16* kb = region + (size_t)M * Dm;
  u16* vb = region + (size_t)2 * M * Dm;
  u16* ab = region + (size_t)3 * M * Dm;
  u16* ffmid = region;

  dim3 blk(256);
  // weight transposes (bf16, N x K)
  for (int i = 0; i < 8; ++i)
    transpose_cast<<<dim3(Dm / 32, Dm / 32), blk, 0, stream>>>(W_in[i], wt[i], Dm, Dm);
  transpose_cast<<<dim3(Dm / 32, F / 32), blk, 0, stream>>>(W_in[8], wt[8], Dm, F);
  transpose_cast<<<dim3(F / 32, Dm / 32), blk, 0, stream>>>(W_in[9], wt[9], F, Dm);
  cast_f32_bf16<<<dim3((M * Dm / 4) / 256), blk, 0, stream>>>(enc, encb, M * Dm / 4);

  dim3 gproj(M / 128, Dm / 128);
  dim3 gffn1(M / 128, F / 128);
  dim3 gattn(T / 64, B * NHEADS);

  // --- self-attention block ---
  ln_bf16<<<M, blk, 0, stream>>>(x, (const float*)d_in[22], (const float*)d_in[23], h);
  gemm_bf16<0><<<gproj, blk, 0, stream>>>(h, wt[0], (const float*)d_in[3], nullptr, qb, nullptr, M, Dm, Dm);
  gemm_bf16<0><<<gproj, blk, 0, stream>>>(h, wt[1], (const float*)d_in[5], nullptr, kb, nullptr, M, Dm, Dm);
  gemm_bf16<0><<<gproj, blk, 0, stream>>>(h, wt[2], (const float*)d_in[7], nullptr, vb, nullptr, M, Dm, Dm);
  attn_kernel<true><<<gattn, blk, 0, stream>>>(qb, kb, vb, ab, T, S);
  gemm_bf16<2><<<gproj, blk, 0, stream>>>(ab, wt[3], (const float*)d_in[9], x, nullptr, xc, M, Dm, Dm);

  // --- cross-attention block ---
  ln_bf16<<<M, blk, 0, stream>>>(xc, (const float*)d_in[24], (const float*)d_in[25], h);
  gemm_bf16<0><<<gproj, blk, 0, stream>>>(h,    wt[4], (const float*)d_in[11], nullptr, qb, nullptr, M, Dm, Dm);
  gemm_bf16<0><<<gproj, blk, 0, stream>>>(encb, wt[5], (const float*)d_in[13], nullptr, kb, nullptr, M, Dm, Dm);
  gemm_bf16<0><<<gproj, blk, 0, stream>>>(encb, wt[6], (const float*)d_in[15], nullptr, vb, nullptr, M, Dm, Dm);
  attn_kernel<false><<<gattn, blk, 0, stream>>>(qb, kb, vb, ab, T, S);
  gemm_bf16<2><<<gproj, blk, 0, stream>>>(ab, wt[7], (const float*)d_in[17], xc, nullptr, xc, M, Dm, Dm);

  // --- FFN block ---
  ln_bf16<<<M, blk, 0, stream>>>(xc, (const float*)d_in[26], (const float*)d_in[27], h);
  gemm_bf16<1><<<gffn1, blk, 0, stream>>>(h, wt[8], (const float*)d_in[19], nullptr, ffmid, nullptr, M, F, Dm);
  gemm_bf16<2><<<gproj, blk, 0, stream>>>(ffmid, wt[9], (const float*)d_in[21], xc, nullptr, (float*)d_out, M, Dm, F);
}

// Round 2
// 989.159 us; speedup vs baseline: 1.2796x; 1.2796x over previous
//
#include <hip/hip_runtime.h>
#include <stdint.h>

#define D_MODEL 1024
#define D_FF    4096
#define NHEADS  16
#define HD      64
#define LN_EPS  1e-5f

using u16 = unsigned short;
typedef __bf16 bf16x8 __attribute__((ext_vector_type(8)));
typedef float  f32x4  __attribute__((ext_vector_type(4)));

typedef __attribute__((address_space(1))) uint32_t as1_u32;
typedef __attribute__((address_space(3))) uint32_t as3_u32;

__device__ __forceinline__ u16 f2bf(float f) {
  union { float f; uint32_t u; } v; v.f = f;
  uint32_t r = v.u + 0x7FFFu + ((v.u >> 16) & 1u);
  return (u16)(r >> 16);
}

// async global->LDS, 16B per lane; LDS dest must be wave-uniform base (+lane*16 implicit)
__device__ __forceinline__ void gl_lds16(const void* g, void* l) {
  __builtin_amdgcn_global_load_lds((const as1_u32*)(uintptr_t)g,
                                   (as3_u32*)(uint32_t)(uintptr_t)l, 16, 0, 0);
}

// ---------------- transpose + cast: W (K x N, f32) -> Wt (N x K, bf16) ----------------
__global__ __launch_bounds__(256)
void transpose_cast(const float* __restrict__ W, u16* __restrict__ Wt, int K, int N) {
  __shared__ float t[32][33];
  const int k0 = blockIdx.x * 32, n0 = blockIdx.y * 32;
  const int x = threadIdx.x & 31, y = threadIdx.x >> 5; // y in 0..7
#pragma unroll
  for (int j = 0; j < 32; j += 8)
    t[y + j][x] = W[(size_t)(k0 + y + j) * N + (n0 + x)];
  __syncthreads();
#pragma unroll
  for (int j = 0; j < 32; j += 8)
    Wt[(size_t)(n0 + y + j) * K + (k0 + x)] = f2bf(t[x][y + j]);
}

// ---------------- elementwise cast f32 -> bf16 ----------------
__global__ __launch_bounds__(256)
void cast_f32_bf16(const float* __restrict__ in, u16* __restrict__ out, int n4) {
  int i = blockIdx.x * 256 + threadIdx.x;
  if (i < n4) {
    float4 v = ((const float4*)in)[i];
    ushort4 o;
    o.x = f2bf(v.x); o.y = f2bf(v.y); o.z = f2bf(v.z); o.w = f2bf(v.w);
    ((ushort4*)out)[i] = o;
  }
}

// ---------------- LayerNorm (fp32 in, bf16 out), one block per row, D=1024 ----------------
__global__ __launch_bounds__(256)
void ln_bf16(const float* __restrict__ x, const float* __restrict__ g,
             const float* __restrict__ bta, u16* __restrict__ out) {
  const int row = blockIdx.x;
  const int tid = threadIdx.x;
  const float4 v = ((const float4*)(x + (size_t)row * D_MODEL))[tid];
  float s  = v.x + v.y + v.z + v.w;
  float s2 = v.x * v.x + v.y * v.y + v.z * v.z + v.w * v.w;
#pragma unroll
  for (int off = 1; off < 64; off <<= 1) {
    s  += __shfl_xor(s, off);
    s2 += __shfl_xor(s2, off);
  }
  __shared__ float sm[8];
  const int wave = tid >> 6, lane = tid & 63;
  if (lane == 0) { sm[wave] = s; sm[4 + wave] = s2; }
  __syncthreads();
  s  = sm[0] + sm[1] + sm[2] + sm[3];
  s2 = sm[4] + sm[5] + sm[6] + sm[7];
  const float mean = s * (1.f / D_MODEL);
  const float var  = s2 * (1.f / D_MODEL) - mean * mean;
  const float rstd = rsqrtf(var + LN_EPS);
  const float4 gv = ((const float4*)g)[tid];
  const float4 bv = ((const float4*)bta)[tid];
  ushort4 o;
  o.x = f2bf((v.x - mean) * rstd * gv.x + bv.x);
  o.y = f2bf((v.y - mean) * rstd * gv.y + bv.y);
  o.z = f2bf((v.z - mean) * rstd * gv.z + bv.z);
  o.w = f2bf((v.w - mean) * rstd * gv.w + bv.w);
  ((ushort4*)(out + (size_t)row * D_MODEL))[tid] = o;
}

// ---------------- GEMM: C[M,N] = A[M,K](bf16) * Wt[N,K]^T(bf16) + bias, epilogues ----------------
// EPI 0: out bf16;  EPI 1: relu -> bf16;  EPI 2: f32 out = acc + bias + resid
template<int EPI>
__global__ __launch_bounds__(256, 2)
void gemm_bf16(const u16* __restrict__ A, const u16* __restrict__ Wt,
               const float* __restrict__ bias, const float* resid,
               u16* __restrict__ outb, float* outf,
               int M, int N, int K) {
  __shared__ u16 lA[128 * 32];
  __shared__ u16 lB[128 * 32];
  const int tid  = threadIdx.x;
  const int lane = tid & 63;
  const int wave = tid >> 6;
  const int wr = wave >> 1, wc = wave & 1;
  const int lr = lane & 15, lg = lane >> 4;
  const int row0 = blockIdx.x * 128, col0 = blockIdx.y * 128;

  // staging: LDS [128][32] bf16 linear; thread covers 16B at linear byte tid*16 (+4096 for chunk 1)
  const char* pa = (const char*)A  + ((size_t)(row0 + (tid >> 2)) * K + (size_t)(tid & 3) * 8) * 2;
  const char* pb = (const char*)Wt + ((size_t)(col0 + (tid >> 2)) * K + (size_t)(tid & 3) * 8) * 2;
  const size_t rowskip = (size_t)64 * K * 2;
  char* la = (char*)lA + wave * 1024;
  char* lb = (char*)lB + wave * 1024;

  f32x4 acc[4][4] = {};
  const int ksteps = K >> 5;
  for (int kt = 0; kt < ksteps; ++kt) {
    gl_lds16(pa, la);
    gl_lds16(pa + rowskip, la + 4096);
    gl_lds16(pb, lb);
    gl_lds16(pb + rowskip, lb + 4096);
    pa += 64; pb += 64;
    __syncthreads();
    bf16x8 af[4], bfr[4];
#pragma unroll
    for (int m = 0; m < 4; ++m)
      af[m] = *(const bf16x8*)((const char*)lA + (wr * 64 + m * 16 + lr) * 64 + lg * 16);
#pragma unroll
    for (int n = 0; n < 4; ++n)
      bfr[n] = *(const bf16x8*)((const char*)lB + (wc * 64 + n * 16 + lr) * 64 + lg * 16);
#pragma unroll
    for (int m = 0; m < 4; ++m)
#pragma unroll
      for (int n = 0; n < 4; ++n)
        acc[m][n] = __builtin_amdgcn_mfma_f32_16x16x32_bf16(af[m], bfr[n], acc[m][n], 0, 0, 0);
    __syncthreads();
  }

#pragma unroll
  for (int m = 0; m < 4; ++m) {
    const int grow = row0 + wr * 64 + m * 16 + lg * 4;
#pragma unroll
    for (int n = 0; n < 4; ++n) {
      const int gcol = col0 + wc * 64 + n * 16 + lr;
      const float bv = bias[gcol];
#pragma unroll
      for (int r = 0; r < 4; ++r) {
        const size_t idx = (size_t)(grow + r) * N + gcol;
        float v = acc[m][n][r] + bv;
        if (EPI == 0)      outb[idx] = f2bf(v);
        else if (EPI == 1) outb[idx] = f2bf(v > 0.f ? v : 0.f);
        else               outf[idx] = v + resid[idx];
      }
    }
  }
}

// ---------------- Flash attention: 64 q-rows per block, 64-wide KV tiles ----------------
// Q,K,V,O: (B*rows, D_MODEL) bf16, head h at column h*HD
// All LDS tiles are 64 rows x 128B; XOR-swizzled at 16B granularity to kill bank conflicts:
//   lQ/lK/lP: granule ^= (row & 7)      (reads have row = base+lr -> spreads over 8 granules)
//   lVt:      granule ^= ((row>>3) & 7) (transpose-write has row&7 wave-uniform; row>>3 varies)
template<bool CAUSAL>
__global__ __launch_bounds__(256, 2)
void attn_kernel(const u16* __restrict__ Q, const u16* __restrict__ Kb,
                 const u16* __restrict__ Vb, u16* __restrict__ O,
                 int T, int S) {
  __shared__ u16 lQ[64 * 64];
  __shared__ u16 lK[64 * 64];
  __shared__ u16 lVt[64 * 64];   // transposed: [d][key], swizzled
  __shared__ u16 lP[4 * 16 * 64]; // per-wave 16x64, swizzled

  const int bh = blockIdx.y;
  const int b = bh / NHEADS, h = bh % NHEADS;
  const int q0 = blockIdx.x * 64;
  const int tid = threadIdx.x, lane = tid & 63, wave = tid >> 6;
  const int lr = lane & 15, lg = lane >> 4;

  const u16* Qbase = Q  + (size_t)(b * T) * D_MODEL + h * HD;
  const u16* Kbase = Kb + (size_t)(b * S) * D_MODEL + h * HD;
  const u16* Vbase = Vb + (size_t)(b * S) * D_MODEL + h * HD;
  const size_t rskip = (size_t)32 * D_MODEL * 2; // 32 rows in bytes

  // staging geometry: lane covers LDS slot (row = tid>>3, granule = tid&7);
  // pre-swizzle the GLOBAL source column so LDS slot g holds global granule g^(row&7)
  const int srow = tid >> 3;
  const int sg   = (tid & 7) ^ (srow & 7);

  // stage Q tile (64 rows x 64 cols bf16, 128B/row)
  {
    const char* src = (const char*)(Qbase + (size_t)(q0 + srow) * D_MODEL) + sg * 16;
    char* dst = (char*)lQ + wave * 1024;
    gl_lds16(src, dst);
    gl_lds16(src + rskip, dst + 4096);
  }

  f32x4 oacc[4] = {};
  float m_run[4], l_run[4];
#pragma unroll
  for (int r = 0; r < 4; ++r) { m_run[r] = -1e30f; l_run[r] = 0.f; }

  const int ktEnd = CAUSAL ? (q0 / 64 + 1) : (S / 64);
  for (int kt = 0; kt < ktEnd; ++kt) {
    // stage K tile (pre-swizzled source)
    {
      const char* src = (const char*)(Kbase + (size_t)(kt * 64 + srow) * D_MODEL) + sg * 16;
      char* dst = (char*)lK + wave * 1024;
      gl_lds16(src, dst);
      gl_lds16(src + rskip, dst + 4096);
    }
    // stage V transposed (manual), swizzled by (d>>3)&7
    {
      const u16* src = Vbase + (size_t)(kt * 64 + (tid >> 3)) * D_MODEL + (tid & 7) * 8;
      union { uint4 q; u16 s[8]; } v0, v1;
      v0.q = *(const uint4*)(src);
      v1.q = *(const uint4*)(src + 32 * D_MODEL);
      const int key = tid >> 3, dbase = (tid & 7) * 8;
      const int kg0 = key >> 3, kb0 = (key & 7) * 2;        // chunk 0: keys 0..31
      const int kg1 = kg0 + 4;                               // chunk 1: keys 32..63
#pragma unroll
      for (int j = 0; j < 8; ++j) {
        const int d = dbase + j;
        const int sw = (d >> 3) & 7;
        char* base = (char*)lVt + d * 128;
        *(u16*)(base + ((kg0 ^ sw) << 4) + kb0) = v0.s[j];
        *(u16*)(base + ((kg1 ^ sw) << 4) + kb0) = v1.s[j];
      }
    }
    __syncthreads();

    // QK^T for this wave's 16 rows x 64 cols
    f32x4 s[4];
    {
      bf16x8 qf[2];
      const int qrow = wave * 16 + lr;
#pragma unroll
      for (int kk = 0; kk < 2; ++kk)
        qf[kk] = *(const bf16x8*)((const char*)lQ + qrow * 128 +
                                  (((kk * 4 + lg) ^ (qrow & 7)) << 4));
#pragma unroll
      for (int n = 0; n < 4; ++n) {
        f32x4 z = {};
        const int krow = n * 16 + lr;
#pragma unroll
        for (int kk = 0; kk < 2; ++kk) {
          bf16x8 kf = *(const bf16x8*)((const char*)lK + krow * 128 +
                                       (((kk * 4 + lg) ^ (krow & 7)) << 4));
          z = __builtin_amdgcn_mfma_f32_16x16x32_bf16(qf[kk], kf, z, 0, 0, 0);
        }
        s[n] = z;
      }
    }
    const float scale = 0.125f; // 1/sqrt(64)
    const bool needMask = CAUSAL && (kt * 64 + 63 > q0);
#pragma unroll
    for (int n = 0; n < 4; ++n)
#pragma unroll
      for (int r = 0; r < 4; ++r) {
        float v = s[n][r] * scale;
        if (needMask) {
          int qpos = q0 + wave * 16 + lg * 4 + r;
          int kpos = kt * 64 + n * 16 + lr;
          if (kpos > qpos) v = -1e30f;
        }
        s[n][r] = v;
      }
    // online softmax (per row; row owned by the 16 lanes with equal lg, at reg r)
#pragma unroll
    for (int r = 0; r < 4; ++r) {
      float mx = fmaxf(fmaxf(s[0][r], s[1][r]), fmaxf(s[2][r], s[3][r]));
      mx = fmaxf(mx, __shfl_xor(mx, 1));
      mx = fmaxf(mx, __shfl_xor(mx, 2));
      mx = fmaxf(mx, __shfl_xor(mx, 4));
      mx = fmaxf(mx, __shfl_xor(mx, 8));
      const float mn = fmaxf(m_run[r], mx);
      const float scl = __expf(m_run[r] - mn);
      m_run[r] = mn;
      float sum = 0.f;
#pragma unroll
      for (int n = 0; n < 4; ++n) {
        float pv = __expf(s[n][r] - mn);
        s[n][r] = pv;
        sum += pv;
      }
      sum += __shfl_xor(sum, 1);
      sum += __shfl_xor(sum, 2);
      sum += __shfl_xor(sum, 4);
      sum += __shfl_xor(sum, 8);
      l_run[r] = l_run[r] * scl + sum;
#pragma unroll
      for (int n2 = 0; n2 < 4; ++n2) oacc[n2][r] *= scl;
    }
    // write P (bf16) to this wave's LDS region, swizzled: granule ^= (row&7)
#pragma unroll
    for (int r = 0; r < 4; ++r) {
      const int prow = lg * 4 + r;
      char* base = (char*)lP + wave * 2048 + prow * 128;
#pragma unroll
      for (int n = 0; n < 4; ++n) {
        const int g = (2 * n + (lr >> 3)) ^ (prow & 7);
        *(u16*)(base + (g << 4) + (lr & 7) * 2) = f2bf(s[n][r]);
      }
    }
    asm volatile("s_waitcnt lgkmcnt(0)" ::: "memory");
    __builtin_amdgcn_sched_barrier(0);
    // PV: oacc += P(16x64) * V(64x64)
#pragma unroll
    for (int kk = 0; kk < 2; ++kk) {
      bf16x8 pf = *(const bf16x8*)((const char*)lP + wave * 2048 + lr * 128 +
                                   (((kk * 4 + lg) ^ (lr & 7)) << 4));
#pragma unroll
      for (int n = 0; n < 4; ++n) {
        const int vrow = n * 16 + lr;
        bf16x8 vf = *(const bf16x8*)((const char*)lVt + vrow * 128 +
                                     (((kk * 4 + lg) ^ ((vrow >> 3) & 7)) << 4));
        oacc[n] = __builtin_amdgcn_mfma_f32_16x16x32_bf16(pf, vf, oacc[n], 0, 0, 0);
      }
    }
    __syncthreads();
  }

  u16* Obase = O + (size_t)(b * T + q0) * D_MODEL + h * HD;
#pragma unroll
  for (int n = 0; n < 4; ++n)
#pragma unroll
    for (int r = 0; r < 4; ++r) {
      float v = oacc[n][r] / l_run[r];
      Obase[(size_t)(wave * 16 + lg * 4 + r) * D_MODEL + n * 16 + lr] = f2bf(v);
    }
}

// ---------------- host ----------------
extern "C" void kernel_launch(void* const* d_in, const int* in_sizes, int n_in,
                              void* d_out, int out_size, void* d_ws, size_t ws_size,
                              hipStream_t stream) {
  (void)in_sizes; (void)n_in; (void)out_size; (void)ws_size;
  const int B = 4, T = 2048, S = 2048, Dm = 1024, F = 4096;
  const int M = B * T;

  const float* x   = (const float*)d_in[0];
  const float* enc = (const float*)d_in[1];
  const float* W_in[10] = {
    (const float*)d_in[2],  (const float*)d_in[4],  (const float*)d_in[6],  (const float*)d_in[8],
    (const float*)d_in[10], (const float*)d_in[12], (const float*)d_in[14], (const float*)d_in[16],
    (const float*)d_in[18], (const float*)d_in[20]
  };

  char* p = (char*)d_ws;
  auto take = [&](size_t bytes) { char* r = p; p += (bytes + 255) & ~(size_t)255; return r; };
  u16* wt[10];
  for (int i = 0; i < 8; ++i) wt[i] = (u16*)take((size_t)Dm * Dm * 2);
  wt[8] = (u16*)take((size_t)F * Dm * 2);   // ff1T: F x Dm
  wt[9] = (u16*)take((size_t)Dm * F * 2);   // ff2T: Dm x F
  u16*   h    = (u16*)take((size_t)M * Dm * 2);
  u16*   encb = (u16*)take((size_t)M * Dm * 2);
  float* xc   = (float*)take((size_t)M * Dm * 4);
  u16*   region = (u16*)take((size_t)M * F * 2);   // q/k/v/attn OR ffmid
  u16* qb = region;
  u16* kb = region + (size_t)M * Dm;
  u16* vb = region + (size_t)2 * M * Dm;
  u16* ab = region + (size_t)3 * M * Dm;
  u16* ffmid = region;

  dim3 blk(256);
  // weight transposes (bf16, N x K)
  for (int i = 0; i < 8; ++i)
    transpose_cast<<<dim3(Dm / 32, Dm / 32), blk, 0, stream>>>(W_in[i], wt[i], Dm, Dm);
  transpose_cast<<<dim3(Dm / 32, F / 32), blk, 0, stream>>>(W_in[8], wt[8], Dm, F);
  transpose_cast<<<dim3(F / 32, Dm / 32), blk, 0, stream>>>(W_in[9], wt[9], F, Dm);
  cast_f32_bf16<<<dim3((M * Dm / 4) / 256), blk, 0, stream>>>(enc, encb, M * Dm / 4);

  dim3 gproj(M / 128, Dm / 128);
  dim3 gffn1(M / 128, F / 128);
  dim3 gattn(T / 64, B * NHEADS);

  // --- self-attention block ---
  ln_bf16<<<M, blk, 0, stream>>>(x, (const float*)d_in[22], (const float*)d_in[23], h);
  gemm_bf16<0><<<gproj, blk, 0, stream>>>(h, wt[0], (const float*)d_in[3], nullptr, qb, nullptr, M, Dm, Dm);
  gemm_bf16<0><<<gproj, blk, 0, stream>>>(h, wt[1], (const float*)d_in[5], nullptr, kb, nullptr, M, Dm, Dm);
  gemm_bf16<0><<<gproj, blk, 0, stream>>>(h, wt[2], (const float*)d_in[7], nullptr, vb, nullptr, M, Dm, Dm);
  attn_kernel<true><<<gattn, blk, 0, stream>>>(qb, kb, vb, ab, T, S);
  gemm_bf16<2><<<gproj, blk, 0, stream>>>(ab, wt[3], (const float*)d_in[9], x, nullptr, xc, M, Dm, Dm);

  // --- cross-attention block ---
  ln_bf16<<<M, blk, 0, stream>>>(xc, (const float*)d_in[24], (const float*)d_in[25], h);
  gemm_bf16<0><<<gproj, blk, 0, stream>>>(h,    wt[4], (const float*)d_in[11], nullptr, qb, nullptr, M, Dm, Dm);
  gemm_bf16<0><<<gproj, blk, 0, stream>>>(encb, wt[5], (const float*)d_in[13], nullptr, kb, nullptr, M, Dm, Dm);
  gemm_bf16<0><<<gproj, blk, 0, stream>>>(encb, wt[6], (const float*)d_in[15], nullptr, vb, nullptr, M, Dm, Dm);
  attn_kernel<false><<<gattn, blk, 0, stream>>>(qb, kb, vb, ab, T, S);
  gemm_bf16<2><<<gproj, blk, 0, stream>>>(ab, wt[7], (const float*)d_in[17], xc, nullptr, xc, M, Dm, Dm);

  // --- FFN block ---
  ln_bf16<<<M, blk, 0, stream>>>(xc, (const float*)d_in[26], (const float*)d_in[27], h);
  gemm_bf16<1><<<gffn1, blk, 0, stream>>>(h, wt[8], (const float*)d_in[19], nullptr, ffmid, nullptr, M, F, Dm);
  gemm_bf16<2><<<gproj, blk, 0, stream>>>(ffmid, wt[9], (const float*)d_in[21], xc, nullptr, (float*)d_out, M, Dm, F);
}